// Round 12
// baseline (188.083 us; speedup 1.0000x reference)
//
#include <hip/hip_runtime.h>

typedef unsigned short ushort_t;
typedef __bf16 bf16x8 __attribute__((ext_vector_type(8)));
typedef short short4v __attribute__((ext_vector_type(4)));
typedef float f32x4 __attribute__((ext_vector_type(4)));
typedef unsigned int uint4v __attribute__((ext_vector_type(4)));
typedef unsigned int uint2v __attribute__((ext_vector_type(2)));

#define NTOK 4096
#define DMODEL 256
#define DK 64
#define BS 8
#define LN2INV 1.44269504088896f

__device__ __forceinline__ ushort_t f2bf(float f) {
  unsigned u = __builtin_bit_cast(unsigned, f);
  u += 0x7fffu + ((u >> 16) & 1u);
  return (ushort_t)(u >> 16);
}
__device__ __forceinline__ float bf2f(ushort_t s) {
  return __builtin_bit_cast(float, ((unsigned)s) << 16);
}
__device__ __forceinline__ bf16x8 lds_frag(const ushort_t* p) {
  return __builtin_bit_cast(bf16x8, *(const uint4v*)p);
}
__device__ __forceinline__ bf16x8 ldg8(const ushort_t* p) {
  return __builtin_bit_cast(bf16x8, *(const uint4v*)p);
}
__device__ __forceinline__ short4v lo8(uint4v v) {
  uint2v t; t.x = v.x; t.y = v.y;
  return __builtin_bit_cast(short4v, t);
}
__device__ __forceinline__ short4v hi8(uint4v v) {
  uint2v t; t.x = v.z; t.y = v.w;
  return __builtin_bit_cast(short4v, t);
}
__device__ __forceinline__ float fexp2(float x) {
#if __has_builtin(__builtin_amdgcn_exp2f)
  return __builtin_amdgcn_exp2f(x);
#else
  return exp2f(x);
#endif
}
// pack hi16(x) | hi16(y)<<16 in one v_perm (bf16 truncation)
__device__ __forceinline__ unsigned bfpack(float x, float y) {
  return __builtin_amdgcn_perm(__builtin_bit_cast(unsigned, y),
                               __builtin_bit_cast(unsigned, x), 0x07060302u);
}
// K=16 bf16 MFMA: A[m=lane&15][k=quad*4+j], B[k=quad*4+j][n=lane&15], C: n=lane&15, m=quad*4+reg
__device__ __forceinline__ f32x4 mfma16(short4v a, short4v b, f32x4 c) {
#if defined(__HIP_DEVICE_COMPILE__)
#if __has_builtin(__builtin_amdgcn_mfma_f32_16x16x16bf16_1k)
  return __builtin_amdgcn_mfma_f32_16x16x16bf16_1k(a, b, c, 0, 0, 0);
#else
  typedef __bf16 bf16x4 __attribute__((ext_vector_type(4)));
  return __builtin_amdgcn_mfma_f32_16x16x16_bf16(__builtin_bit_cast(bf16x4, a),
                                                 __builtin_bit_cast(bf16x4, b), c, 0, 0, 0);
#endif
#else
  (void)a; (void)b;
  return c;  // host pass: never executed
#endif
}

// async global->LDS DMA, 16B per lane; dest = (uniform base) + lane*16
typedef __attribute__((address_space(3))) unsigned int lds_u32;
typedef const __attribute__((address_space(1))) unsigned int glob_u32;
__device__ __forceinline__ void gll16(const void* g, void* l) {
#if defined(__HIP_DEVICE_COMPILE__)
  __builtin_amdgcn_global_load_lds((glob_u32*)g, (lds_u32*)l, 16, 0, 0);
#else
  (void)g; (void)l;
#endif
}

// ----- k_convert: W fp32 -> bf16; Q rows pre-scaled by 1/ln2 (exp2 trick) --
__global__ __launch_bounds__(256) void k_convert(const float* __restrict__ Wqkv,
                                                 const float* __restrict__ Wout,
                                                 ushort_t* __restrict__ Wb,
                                                 ushort_t* __restrict__ Woutb) {
  int i = blockIdx.x * 256 + threadIdx.x;  // 256 blocks: 65536 total
  if (i < 3 * DK * DMODEL) {
    float w = Wqkv[i];
    if (i < DK * DMODEL) w *= LN2INV;  // Q rows
    Wb[i] = f2bf(w);
  } else {
    int j = i - 3 * DK * DMODEL;
    Woutb[j] = f2bf(Wout[j]);
  }
}

// ---------------- k1 v4: qkv = Wqkv @ x ; fused transpose + coalesced out --
__global__ __launch_bounds__(256) void k_qkv(const float* __restrict__ x,
                                             const ushort_t* __restrict__ W,
                                             ushort_t* __restrict__ QT,
                                             ushort_t* __restrict__ KT,
                                             ushort_t* __restrict__ Vf) {
  const int b = blockIdx.y;
  const int n0 = blockIdx.x * 64;
  const int tid = threadIdx.x;
  const int lane = tid & 63, wv = tid >> 6;
  const int quad = lane >> 4, l15 = lane & 15;
  __shared__ __align__(16) ushort_t lx[64 * 264];
  __shared__ __align__(16) ushort_t t[64 * 72];

  const float* xb = x + (size_t)b * DMODEL * NTOK;

  // ---- transpose prologue: 4 chunks of 64 c ----
#pragma unroll 1
  for (int cc = 0; cc < 4; cc++) {
    const int c0chunk = cc * 64;
#pragma unroll
    for (int kr = 0; kr < 2; kr++) {
      int s = tid + 256 * kr;
      int c = s >> 3, ns = (s & 7) * 8;
      const float* src = xb + (size_t)(c0chunk + c) * NTOK + n0 + ns;
      f32x4 a = *(const f32x4*)src;
      f32x4 bq = *(const f32x4*)(src + 4);
      uint4v o;
      o.x = (unsigned)f2bf(a[0]) | ((unsigned)f2bf(a[1]) << 16);
      o.y = (unsigned)f2bf(a[2]) | ((unsigned)f2bf(a[3]) << 16);
      o.z = (unsigned)f2bf(bq[0]) | ((unsigned)f2bf(bq[1]) << 16);
      o.w = (unsigned)f2bf(bq[2]) | ((unsigned)f2bf(bq[3]) << 16);
      *(uint4v*)(t + c * 72 + ns) = o;
    }
    __syncthreads();
#pragma unroll
    for (int kr = 0; kr < 2; kr++) {
      int s = tid + 256 * kr;
      int n = s >> 3, cs = (s & 7) * 8;
      unsigned e0 = t[(cs + 0) * 72 + n], e1 = t[(cs + 1) * 72 + n];
      unsigned e2 = t[(cs + 2) * 72 + n], e3 = t[(cs + 3) * 72 + n];
      unsigned e4 = t[(cs + 4) * 72 + n], e5 = t[(cs + 5) * 72 + n];
      unsigned e6 = t[(cs + 6) * 72 + n], e7 = t[(cs + 7) * 72 + n];
      uint4v o;
      o.x = e0 | (e1 << 16); o.y = e2 | (e3 << 16);
      o.z = e4 | (e5 << 16); o.w = e6 | (e7 << 16);
      *(uint4v*)(lx + n * 264 + c0chunk + cs) = o;
    }
    __syncthreads();
  }

  // ---- main loop: barrier-free ----
  f32x4 acc[3][4];
  const f32x4 zero4 = {0.f, 0.f, 0.f, 0.f};
#pragma unroll
  for (int i = 0; i < 3; i++)
#pragma unroll
    for (int j = 0; j < 4; j++) acc[i][j] = zero4;

#pragma unroll
  for (int c0 = 0; c0 < DMODEL; c0 += 32) {
    bf16x8 aw[3];
#pragma unroll
    for (int mt = 0; mt < 3; mt++)
      aw[mt] = ldg8(W + (wv * 48 + mt * 16 + l15) * DMODEL + c0 + quad * 8);
    bf16x8 bb[4];
#pragma unroll
    for (int nt = 0; nt < 4; nt++)
      bb[nt] = lds_frag(lx + (nt * 16 + l15) * 264 + c0 + quad * 8);
#pragma unroll
    for (int mt = 0; mt < 3; mt++)
#pragma unroll
      for (int nt = 0; nt < 4; nt++)
        acc[mt][nt] = __builtin_amdgcn_mfma_f32_16x16x32_bf16(aw[mt], bb[nt], acc[mt][nt], 0, 0, 0);
  }

  // ---- epilogue: stage in LDS (overlay lx), then coalesced stores ----
  __syncthreads();  // all waves done reading lx
  ushort_t* qk_t = lx;            // 128 rows x 68 shorts (Q rows 0-63, K rows 64-127)
  ushort_t* v_t = lx + 128 * 68;  // 4096 shorts: the block's contiguous Vf tile
#pragma unroll
  for (int mt = 0; mt < 3; mt++) {
    int o = wv * 48 + mt * 16 + quad * 4;
#pragma unroll
    for (int nt = 0; nt < 4; nt++) {
      int nl = nt * 16 + l15;
      f32x4 v4 = acc[mt][nt];
      if (o < 128) {
        uint2v ww;
        ww.x = (unsigned)f2bf(v4[0]) | ((unsigned)f2bf(v4[1]) << 16);
        ww.y = (unsigned)f2bf(v4[2]) | ((unsigned)f2bf(v4[3]) << 16);
        int row = (o < 64) ? nl : 64 + nl;
        *(uint2v*)(qk_t + row * 68 + (o & 63)) = ww;
      } else {
        int dbase = o - 128;
        int idx = (nt * 2 + (dbase >> 5)) * 512 + ((l15 >> 2) << 7) +
                  ((dbase & 15) << 3) + (((dbase >> 4) & 1) << 2) + (l15 & 3);
#pragma unroll
        for (int r = 0; r < 4; r++) v_t[idx + (r << 3)] = f2bf(v4[r]);
      }
    }
  }
  __syncthreads();
  {
    ushort_t* QTb = QT + ((size_t)b * NTOK + n0) * DK;
    ushort_t* KTb = KT + ((size_t)b * NTOK + n0) * DK;
#pragma unroll
    for (int k = 0; k < 4; k++) {
      int s = tid + 256 * k;
      int row = s >> 3, seg = (s & 7) * 8;
      uint4v val = *(const uint4v*)(qk_t + row * 68 + seg);
      ushort_t* dst = (row < 64) ? (QTb + (size_t)row * DK + seg)
                                 : (KTb + (size_t)(row - 64) * DK + seg);
      *(uint4v*)dst = val;
    }
    ushort_t* Vtile = Vf + ((size_t)b * 64 + (n0 >> 6)) * 4096;
    *(uint4v*)(Vtile + tid * 8) = *(const uint4v*)(v_t + tid * 8);
    *(uint4v*)(Vtile + 2048 + tid * 8) = *(const uint4v*)(v_t + 2048 + tid * 8);
  }
}

// ---- k_rsum v7: wave-private async DMA double-buffer for the K stream ----
// 1024 blocks x 256 thr (4 waves). Wave owns 512 j in 16 phases of 32 j.
// Per phase: issue 4 gll16 (phase+1) -> vmcnt(4) drains only the previous
// phase's group (issued ~1 phase earlier, free) -> read own 16B slots ->
// 16 MFMA + exp2. No plain global loads in the loop (no spill). Partials
// (2 j-halves) written without -log2; merge+log2 folds into k_pv prologue.
__global__ __launch_bounds__(256, 4) void k_rsum(const ushort_t* __restrict__ QT,
                                                 const ushort_t* __restrict__ KT,
                                                 float* __restrict__ Rp) {
  const int id = blockIdx.x;                 // 1024 blocks
  const int b = id & 7;                      // XCD affinity
  const int i0 = ((id >> 3) & 63) * 64;
  const int jh = id >> 9;                    // j half
  const int tid = threadIdx.x;
  const int lane = tid & 63, wv = tid >> 6;  // 4 waves
  const int quad = lane >> 4, l15 = lane & 15;

  __shared__ __align__(16) ushort_t pool[16384];  // 32768 B
  ushort_t* wbuf = pool + wv * 4096;              // wave dbuf: 2 x 2048 shorts
  float* partial = (float*)pool;                  // epilogue overlay: 4x64 f32

  const ushort_t* QTb = QT + ((size_t)b * NTOK + i0) * DK;
  const ushort_t* KTb = KT + ((size_t)b * NTOK + jh * 2048 + wv * 512) * DK;

  // prologue: issue phase-0 K DMA (rows l15 and 16+l15, two 32-short halves)
  {
    const ushort_t* kp = KTb + (size_t)l15 * DK + quad * 8;
    gll16(kp,            wbuf);
    gll16(kp + 32,       wbuf + 512);
    gll16(kp + 16 * DK,  wbuf + 1024);
    gll16(kp + 16 * DK + 32, wbuf + 1536);
  }

  // Q fragments for all 64 i's (one-time, coalesced, pre-sync)
  bf16x8 aq0[4], aq1[4];
#pragma unroll
  for (int isub = 0; isub < 4; isub++) {
    const ushort_t* qp = QTb + (size_t)(isub * 16 + l15) * DK + quad * 8;
    aq0[isub] = ldg8(qp);
    aq1[isub] = ldg8(qp + 32);
  }

  __syncthreads();  // drains vmcnt -> buf0 complete; loop counting starts at 0

  f32x4 racc[4];
  const f32x4 zero4 = {0.f, 0.f, 0.f, 0.f};
#pragma unroll
  for (int isub = 0; isub < 4; isub++) racc[isub] = zero4;

#pragma unroll 1
  for (int ph = 0; ph < 16; ph++) {
    const int cb = ph & 1, nb = cb ^ 1;
    const int ppre = (ph + 1 < 16) ? ph + 1 : 15;  // dummy tail keeps vmcnt math
    {
      const ushort_t* kp = KTb + (size_t)(ppre * 32 + l15) * DK + quad * 8;
      ushort_t* nbuf = wbuf + nb * 2048;
      gll16(kp,                nbuf);
      gll16(kp + 32,           nbuf + 512);
      gll16(kp + 16 * DK,      nbuf + 1024);
      gll16(kp + 16 * DK + 32, nbuf + 1536);
    }
    asm volatile("s_waitcnt vmcnt(4)" ::: "memory");  // prev phase's DMA done
    __builtin_amdgcn_sched_barrier(0);
    const ushort_t* cbuf = wbuf + cb * 2048;
    bf16x8 kb00 = lds_frag(cbuf + lane * 8);          // nt0 lo
    bf16x8 kb01 = lds_frag(cbuf + 512 + lane * 8);    // nt0 hi
    bf16x8 kb10 = lds_frag(cbuf + 1024 + lane * 8);   // nt1 lo
    bf16x8 kb11 = lds_frag(cbuf + 1536 + lane * 8);   // nt1 hi
#pragma unroll
    for (int isub = 0; isub < 4; isub++) {
      f32x4 s4 = __builtin_amdgcn_mfma_f32_16x16x32_bf16(aq0[isub], kb00, zero4, 0, 0, 0);
      s4 = __builtin_amdgcn_mfma_f32_16x16x32_bf16(aq1[isub], kb01, s4, 0, 0, 0);
      racc[isub][0] += fexp2(s4[0]);
      racc[isub][1] += fexp2(s4[1]);
      racc[isub][2] += fexp2(s4[2]);
      racc[isub][3] += fexp2(s4[3]);
      f32x4 t4 = __builtin_amdgcn_mfma_f32_16x16x32_bf16(aq0[isub], kb10, zero4, 0, 0, 0);
      t4 = __builtin_amdgcn_mfma_f32_16x16x32_bf16(aq1[isub], kb11, t4, 0, 0, 0);
      racc[isub][0] += fexp2(t4[0]);
      racc[isub][1] += fexp2(t4[1]);
      racc[isub][2] += fexp2(t4[2]);
      racc[isub][3] += fexp2(t4[3]);
    }
  }

  asm volatile("s_waitcnt vmcnt(0)" ::: "memory");  // drain dummy prefetch
  __syncthreads();  // all waves out of dbuf before partial overlay

  // reduce over the 16 j-lanes (l15); quad bits untouched by masks 1,2,4,8
#pragma unroll
  for (int isub = 0; isub < 4; isub++)
#pragma unroll
    for (int r = 0; r < 4; r++) {
      float v = racc[isub][r];
      v += __shfl_xor(v, 1);
      v += __shfl_xor(v, 2);
      v += __shfl_xor(v, 4);
      v += __shfl_xor(v, 8);
      racc[isub][r] = v;
    }
  if (l15 == 0) {
#pragma unroll
    for (int isub = 0; isub < 4; isub++)
      *(f32x4*)(partial + wv * 64 + isub * 16 + quad * 4) = racc[isub];
  }
  __syncthreads();
  if (tid < 64) {
    float s = partial[tid] + partial[64 + tid] + partial[128 + tid] + partial[192 + tid];
    Rp[((size_t)jh * BS + b) * NTOK + i0 + tid] = s;
  }
}

// ---- k_pv v10 (round-11 validated) + Rp-pair merge in the lrtab prologue --
__global__ __launch_bounds__(512, 4) void k_pv(const ushort_t* __restrict__ QT,
                                               const ushort_t* __restrict__ KT,
                                               const ushort_t* __restrict__ Vf,
                                               const float* __restrict__ Rp,
                                               const ushort_t* __restrict__ Wout,
                                               const float* __restrict__ gammap,
                                               const float* __restrict__ x,
                                               float* __restrict__ outp) {
  const int id = blockIdx.x;                 // 512 blocks
  const int b = id & 7;                      // XCD affinity
  const int j0 = (id >> 3) * 64;
  const int tid = threadIdx.x;
  const int lane = tid & 63, wv = tid >> 6;  // 8 waves
  const int quad = lane >> 4, l15 = lane & 15;
  const int ih = wv >> 2, wq = wv & 3;

  __shared__ __align__(16) ushort_t pool[24576];   // 49152 B
  float* lrtab = (float*)pool;                     // [0,16384): 4096 f32
  ushort_t* wbuf = pool + 8192 + wv * 2048;        // byte 16384 + wv*4096
  float* rbufA = (float*)pool;                     // epilogue: bytes [0,17408)
  float* rbufB = (float*)(pool + 8704);            // bytes [17408,34816)
  ushort_t* pbuf = pool + 17408;                   // bytes [34816,44032)

  const ushort_t* KTb = KT + ((size_t)b * NTOK + j0) * DK;
  const ushort_t* QTb = QT + ((size_t)b * NTOK + ih * 2048) * DK;
  const ushort_t* Vfb = Vf + ((size_t)b * 64 + ih * 32) * 4096;  // 8KB tiles

  const int qrow = (wq * 16 + l15) * DK + quad * 8;
  const int vfo = wq * 1024 + lane * 8;

  // issue it0 DMA first (overlaps lr-table staging + K loads)
  gll16(QTb + qrow,       wbuf);
  gll16(QTb + qrow + 32,  wbuf + 512);
  gll16(Vfb + vfo,        wbuf + 1024);
  gll16(Vfb + vfo + 512,  wbuf + 1536);

  // lr table: merge the two j-half partials + -log2, 8 entries per thread
  {
    const float* Rp0 = Rp + (size_t)b * NTOK;
    const float* Rp1 = Rp + (size_t)BS * NTOK + (size_t)b * NTOK;
    f32x4 a0 = *(const f32x4*)(Rp0 + tid * 8);
    f32x4 a1 = *(const f32x4*)(Rp0 + tid * 8 + 4);
    f32x4 b0 = *(const f32x4*)(Rp1 + tid * 8);
    f32x4 b1 = *(const f32x4*)(Rp1 + tid * 8 + 4);
    f32x4 s0, s1;
#pragma unroll
    for (int r = 0; r < 4; r++) {
      s0[r] = -__log2f(a0[r] + b0[r]);
      s1[r] = -__log2f(a1[r] + b1[r]);
    }
    *(f32x4*)(lrtab + tid * 8) = s0;
    *(f32x4*)(lrtab + tid * 8 + 4) = s1;
  }

  // resident K tile, one-time direct-global per wave
  bf16x8 kb0[4], kb1[4];
#pragma unroll
  for (int nt = 0; nt < 4; nt++) {
    const ushort_t* kp = KTb + (size_t)(nt * 16 + l15) * DK + quad * 8;
    kb0[nt] = ldg8(kp);
    kb1[nt] = ldg8(kp + 32);
  }

  __syncthreads();  // lrtab visible; drains vmcnt -> buf0 complete

  f32x4 yt[4][4];
  const f32x4 zero4 = {0.f, 0.f, 0.f, 0.f};
#pragma unroll
  for (int i = 0; i < 4; i++)
#pragma unroll
    for (int j = 0; j < 4; j++) yt[i][j] = zero4;

#pragma unroll 1
  for (int it = 0; it < 32; it++) {
    const int cb = it & 1, nb = cb ^ 1;
    const int tpre = (it + 1 < 32) ? it + 1 : 31;  // always issue (keeps vmcnt math)
    {
      const ushort_t* qp = QTb + (size_t)tpre * 64 * DK + qrow;
      const ushort_t* vp = Vfb + (size_t)tpre * 4096 + vfo;
      ushort_t* nbuf = wbuf + nb * 2048;
      gll16(qp,       nbuf);
      gll16(qp + 32,  nbuf + 512);
      gll16(vp,       nbuf + 1024);
      gll16(vp + 512, nbuf + 1536);
    }
    asm volatile("s_waitcnt vmcnt(4)" ::: "memory");  // prev it's DMA done
    __builtin_amdgcn_sched_barrier(0);
    const ushort_t* cbuf = wbuf + cb * 2048;
    bf16x8 a0 = lds_frag(cbuf + lane * 8);
    bf16x8 a1 = lds_frag(cbuf + 512 + lane * 8);
    uint4v vv0 = *(const uint4v*)(cbuf + 1024 + lane * 8);
    uint4v vv1 = *(const uint4v*)(cbuf + 1536 + lane * 8);
    f32x4 lrv = *(const f32x4*)(lrtab + ih * 2048 + it * 64 + wq * 16 + quad * 4);
    short4v vf0 = lo8(vv0), vf1 = hi8(vv0), vf2 = lo8(vv1), vf3 = hi8(vv1);
#pragma unroll
    for (int nt = 0; nt < 4; nt++) {
      f32x4 s4 = __builtin_amdgcn_mfma_f32_16x16x32_bf16(a0, kb0[nt], lrv, 0, 0, 0);
      s4 = __builtin_amdgcn_mfma_f32_16x16x32_bf16(a1, kb1[nt], s4, 0, 0, 0);
      uint2v wp;
      wp.x = bfpack(fexp2(s4[0]), fexp2(s4[1]));
      wp.y = bfpack(fexp2(s4[2]), fexp2(s4[3]));
      short4v wf = __builtin_bit_cast(short4v, wp);
      yt[nt][0] = mfma16(wf, vf0, yt[nt][0]);
      yt[nt][1] = mfma16(wf, vf1, yt[nt][1]);
      yt[nt][2] = mfma16(wf, vf2, yt[nt][2]);
      yt[nt][3] = mfma16(wf, vf3, yt[nt][3]);
    }
  }

  asm volatile("s_waitcnt vmcnt(0)" ::: "memory");  // drain dummy prefetch
  __syncthreads();  // all waves out of dbuf/lrtab region before overlay

  // two parallel 4-wave reduction chains: group ih=0 -> rbufA, ih=1 -> rbufB
  float* rb = (ih == 0) ? rbufA : rbufB;
  if (wq == 0) {
#pragma unroll
    for (int nt = 0; nt < 4; nt++)
#pragma unroll
      for (int dsub = 0; dsub < 4; dsub++)
        *(f32x4*)(rb + (dsub * 16 + l15) * 68 + nt * 16 + quad * 4) = yt[nt][dsub];
  }
  __syncthreads();
  if (wq == 1) {
#pragma unroll
    for (int nt = 0; nt < 4; nt++)
#pragma unroll
      for (int dsub = 0; dsub < 4; dsub++) {
        float* p = rb + (dsub * 16 + l15) * 68 + nt * 16 + quad * 4;
        *(f32x4*)p = *(const f32x4*)p + yt[nt][dsub];
      }
  }
  __syncthreads();
  if (wq == 2) {
#pragma unroll
    for (int nt = 0; nt < 4; nt++)
#pragma unroll
      for (int dsub = 0; dsub < 4; dsub++) {
        float* p = rb + (dsub * 16 + l15) * 68 + nt * 16 + quad * 4;
        *(f32x4*)p = *(const f32x4*)p + yt[nt][dsub];
      }
  }
  __syncthreads();
  if (wq == 3) {
#pragma unroll
    for (int nt = 0; nt < 4; nt++)
#pragma unroll
      for (int dsub = 0; dsub < 4; dsub++) {
        float* p = rb + (dsub * 16 + l15) * 68 + nt * 16 + quad * 4;
        *(f32x4*)p = *(const f32x4*)p + yt[nt][dsub];
      }
  }
  __syncthreads();
  // combine A+B -> bf16 pbuf[j][d]; wave wv covers nt = wv&3, dsub pair wv>>2
  {
    const int nt = wv & 3;
#pragma unroll
    for (int k = 0; k < 2; k++) {
      const int dsub = (wv >> 2) * 2 + k;
      const float* pA = rbufA + (dsub * 16 + l15) * 68 + nt * 16 + quad * 4;
      const float* pB = rbufB + (dsub * 16 + l15) * 68 + nt * 16 + quad * 4;
      f32x4 v4 = *(const f32x4*)pA + *(const f32x4*)pB;
#pragma unroll
      for (int r = 0; r < 4; r++)
        pbuf[(nt * 16 + quad * 4 + r) * 72 + dsub * 16 + l15] = f2bf(v4[r]);
    }
  }
  __syncthreads();

  // ---- fused projection: o = Wout @ y * gamma + x (k_out body, m-width 2) --
  bf16x8 yb0[4], yb1[4];
#pragma unroll
  for (int nt = 0; nt < 4; nt++) {
    yb0[nt] = lds_frag(pbuf + (nt * 16 + l15) * 72 + quad * 8);
    yb1[nt] = lds_frag(pbuf + (nt * 16 + l15) * 72 + 32 + quad * 8);
  }
  f32x4 oacc[2][4];
#pragma unroll
  for (int m = 0; m < 2; m++)
#pragma unroll
    for (int nt = 0; nt < 4; nt++) oacc[m][nt] = zero4;
#pragma unroll
  for (int m = 0; m < 2; m++) {
    int c = (wv * 2 + m) * 16 + l15;
    bf16x8 aw0 = __builtin_bit_cast(bf16x8, *(const uint4v*)(Wout + c * DK + quad * 8));
    bf16x8 aw1 = __builtin_bit_cast(bf16x8, *(const uint4v*)(Wout + c * DK + 32 + quad * 8));
#pragma unroll
    for (int nt = 0; nt < 4; nt++) {
      oacc[m][nt] = __builtin_amdgcn_mfma_f32_16x16x32_bf16(aw0, yb0[nt], oacc[m][nt], 0, 0, 0);
      oacc[m][nt] = __builtin_amdgcn_mfma_f32_16x16x32_bf16(aw1, yb1[nt], oacc[m][nt], 0, 0, 0);
    }
  }
  float g = gammap[0];
  const float* xb = x + (size_t)b * DMODEL * NTOK;
  float* ob = outp + (size_t)b * DMODEL * NTOK;
#pragma unroll
  for (int m = 0; m < 2; m++) {
    int cbase = (wv * 2 + m) * 16 + quad * 4;
#pragma unroll
    for (int nt = 0; nt < 4; nt++) {
      int n = j0 + nt * 16 + l15;
#pragma unroll
      for (int r = 0; r < 4; r++) {
        size_t idx = (size_t)(cbase + r) * NTOK + n;
        ob[idx] = oacc[m][nt][r] * g + xb[idx];
      }
    }
  }
}

extern "C" void kernel_launch(void* const* d_in, const int* in_sizes, int n_in,
                              void* d_out, int out_size, void* d_ws, size_t ws_size,
                              hipStream_t stream) {
  const float* v = (const float*)d_in[0];
  const float* Wqkv = (const float*)d_in[1];
  const float* Wout = (const float*)d_in[2];
  const float* gamma = (const float*)d_in[3];
  float* outp = (float*)d_out;

  ushort_t* QT = (ushort_t*)d_ws;                      // 8*4096*64 bf16
  ushort_t* KT = QT + (size_t)BS * NTOK * DK;
  ushort_t* Vf = KT + (size_t)BS * NTOK * DK;          // fragment-order V
  ushort_t* Wb = Vf + (size_t)BS * DK * NTOK;          // 192*256
  ushort_t* Woutb = Wb + 3 * DK * DMODEL;              // 256*64
  float* Rp = (float*)(Woutb + DMODEL * DK);           // 2 x 8*4096 f32 partials

  k_convert<<<dim3(256), 256, 0, stream>>>(Wqkv, Wout, Wb, Woutb);
  k_qkv<<<dim3(64, BS), 256, 0, stream>>>(v, Wb, QT, KT, Vf);
  k_rsum<<<dim3(1024), 256, 0, stream>>>(QT, KT, Rp);
  k_pv<<<dim3(512), 512, 0, stream>>>(QT, KT, Vf, Rp, Woutb, gamma, v, outp);
}